// Round 2
// baseline (618.495 us; speedup 1.0000x reference)
//
#include <hip/hip_runtime.h>
#include <math.h>

static constexpr int M_ROWS   = 200000;
static constexpr int NUM_NODE = 150;
static constexpr int TPB      = 256;
static constexpr int NBLOCKS  = 2048;                   // persistent grid
static constexpr int NWAVES   = NBLOCKS * (TPB / 64);   // 8192 waves

__global__ __launch_bounds__(TPB, 4) void obstacle_to_lane_kernel(
    const float* __restrict__ lf,       // (M, 150, 4) f32
    const float* __restrict__ obs,      // (N, 2) f32
    const int*   __restrict__ mask,     // (M, 1) i32
    float*       __restrict__ out)      // [M*2 proj | M*2 idx | M*2 rep]
{
    const int lane = threadIdx.x & 63;
    const int gw   = (int)((blockIdx.x * TPB + threadIdx.x) >> 6);

    // node indices this lane scans (valid range 1..148)
    const int  j0 = 1 + lane;
    const int  j1 = 65 + lane;
    const bool v2 = (129 + lane) <= (NUM_NODE - 2);
    const int  j2 = v2 ? (129 + lane) : (NUM_NODE - 2);  // clamped (dup load, same lines)

    int r = gw;
    if (r >= M_ROWS) return;

    // ---- prologue: prefetch row r ----
    const float* rp = lf + (size_t)r * (NUM_NODE * 4);
    int    nmask = mask[__builtin_amdgcn_readfirstlane(r)];   // scalar path
    float4 n0 = *reinterpret_cast<const float4*>(rp + 4 * j0);
    float4 n1 = *reinterpret_cast<const float4*>(rp + 4 * j1);
    float4 n2 = *reinterpret_cast<const float4*>(rp + 4 * j2);

    for (;;) {
        const int rc = r;
        r += NWAVES;
        const bool more = (r < M_ROWS);   // wave-uniform

        // snapshot current row's data (compiler renames; wait is for last iter's loads)
        const int    mcur = nmask;
        const float4 a0 = n0, a1 = n1, a2 = n2;

        // ---- prefetch next row BEFORE any compute stalls ----
        if (more) {
            const float* np = lf + (size_t)r * (NUM_NODE * 4);
            nmask = mask[__builtin_amdgcn_readfirstlane(r)];
            n0 = *reinterpret_cast<const float4*>(np + 4 * j0);
            n1 = *reinterpret_cast<const float4*>(np + 4 * j1);
            n2 = *reinterpret_cast<const float4*>(np + 4 * j2);
        }

        // obs gather for current row — scalar s_load path (mcur is SGPR)
        const float rx = obs[2 * mcur];
        const float ry = obs[2 * mcur + 1];

        // ---- argmin over nodes 1..148 of (x-rx)^2 + (y-ry)^2 ----
        // key = (f32_bits(d) << 32) | j ; d >= 0 so bits are order-monotone.
        // u64 min gives min-d with first-occurrence (smallest j) tiebreak.
        unsigned long long key;
        {
            float dx, dy, d;
            dx = __fsub_rn(a0.x, rx); dy = __fsub_rn(a0.y, ry);
            d  = __fadd_rn(__fmul_rn(dx, dx), __fmul_rn(dy, dy));
            key = ((unsigned long long)__float_as_uint(d) << 32) | (unsigned)j0;

            dx = __fsub_rn(a1.x, rx); dy = __fsub_rn(a1.y, ry);
            d  = __fadd_rn(__fmul_rn(dx, dx), __fmul_rn(dy, dy));
            unsigned long long k1 = ((unsigned long long)__float_as_uint(d) << 32) | (unsigned)j1;
            if (k1 < key) key = k1;

            dx = __fsub_rn(a2.x, rx); dy = __fsub_rn(a2.y, ry);
            d  = __fadd_rn(__fmul_rn(dx, dx), __fmul_rn(dy, dy));
            unsigned long long k2 = ((unsigned long long)__float_as_uint(d) << 32) | (unsigned)j2;
            if (v2 && k2 < key) key = k2;
        }
        #pragma unroll
        for (int off = 32; off > 0; off >>= 1) {
            const unsigned long long o = __shfl_down(key, off, 64);
            if (o < key) key = o;
        }
        const int min_idx = (int)(unsigned)__shfl(key, 0, 64);

        if (lane == 0) {
            const float* rowc = lf + (size_t)rc * (NUM_NODE * 4);
            // neighbor rows: lines fetched ~1 iteration ago -> L1/L2 hit
            const float4 a = *reinterpret_cast<const float4*>(rowc + 4 * (min_idx - 1));
            const float4 c = *reinterpret_cast<const float4*>(rowc + 4 * min_idx);
            const float4 b = *reinterpret_cast<const float4*>(rowc + 4 * (min_idx + 1));

            float t, s;
            t = __fsub_rn(a.x, c.x); s = __fmul_rn(t, t);
            t = __fsub_rn(a.y, c.y); s = __fadd_rn(s, __fmul_rn(t, t));
            t = __fsub_rn(a.z, c.z); s = __fadd_rn(s, __fmul_rn(t, t));
            t = __fsub_rn(a.w, c.w); s = __fadd_rn(s, __fmul_rn(t, t));
            const float dist_prev = s;
            t = __fsub_rn(b.x, c.x); s = __fmul_rn(t, t);
            t = __fsub_rn(b.y, c.y); s = __fadd_rn(s, __fmul_rn(t, t));
            t = __fsub_rn(b.z, c.z); s = __fadd_rn(s, __fmul_rn(t, t));
            t = __fsub_rn(b.w, c.w); s = __fadd_rn(s, __fmul_rn(t, t));
            const float dist_next = s;

            float sx, sy, ex, ey; int ib;
            if (dist_next < dist_prev) {         // before=min_idx, after=min_idx+1
                ib = min_idx;     sx = c.x; sy = c.y; ex = b.x; ey = b.y;
            } else {                              // before=min_idx-1, after=min_idx
                ib = min_idx - 1; sx = a.x; sy = a.y; ex = c.x; ey = c.y;
            }

            const float lvx = __fsub_rn(ex, sx);
            const float lvy = __fsub_rn(ey, sy);
            const float mag = __fsqrt_rn(__fadd_rn(__fmul_rn(lvx, lvx), __fmul_rn(lvy, lvy)));
            const float ux  = __fdiv_rn(lvx, mag);
            const float uy  = __fdiv_rn(lvy, mag);
            const float pm  = __fadd_rn(__fmul_rn(__fsub_rn(rx, sx), ux),
                                        __fmul_rn(__fsub_rn(ry, sy), uy));
            const float px  = __fadd_rn(sx, __fmul_rn(pm, ux));
            const float py  = __fadd_rn(sy, __fmul_rn(pm, uy));

            float* o_proj = out + 2 * (size_t)rc;
            o_proj[0] = px; o_proj[1] = py;
            float* o_idx = out + 2 * (size_t)M_ROWS + 2 * (size_t)rc;
            o_idx[0] = (float)ib; o_idx[1] = (float)(ib + 1);
            float* o_rep = out + 4 * (size_t)M_ROWS + 2 * (size_t)rc;
            o_rep[0] = rx; o_rep[1] = ry;
        }

        if (!more) break;
    }
}

extern "C" void kernel_launch(void* const* d_in, const int* in_sizes, int n_in,
                              void* d_out, int out_size, void* d_ws, size_t ws_size,
                              hipStream_t stream) {
    const float* lf      = (const float*)d_in[0];
    const float* obs_pos = (const float*)d_in[1];
    const int*   mask    = (const int*)d_in[2];
    float*       out     = (float*)d_out;

    hipLaunchKernelGGL(obstacle_to_lane_kernel, dim3(NBLOCKS), dim3(TPB), 0, stream,
                       lf, obs_pos, mask, out);
}